// Round 1
// baseline (1059.836 us; speedup 1.0000x reference)
//
#include <hip/hip_runtime.h>
#include <math.h>

// TGCN: GCN-normalized aggregation (3 gates) + GRU cell + pooled decoder.
// All fp32. CSR-by-dst built on device to avoid float atomic scatter.

#define HD 128
#define G3 384

__global__ void init_deg_kernel(float* deg, int n) {
    int i = blockIdx.x * blockDim.x + threadIdx.x;
    if (i < n) deg[i] = 1.0f;  // self-loop weight
}

__global__ void edge_accum_kernel(const int* __restrict__ dst,
                                  const float* __restrict__ w,
                                  float* deg, int* counts, int E) {
    int e = blockIdx.x * blockDim.x + threadIdx.x;
    if (e < E) {
        int d = dst[e];
        atomicAdd(&deg[d], w[e]);
        atomicAdd(&counts[d], 1);
    }
}

__global__ void dinv_kernel(const float* __restrict__ deg, float* dinv, int n) {
    int i = blockIdx.x * blockDim.x + threadIdx.x;
    if (i < n) {
        float d = deg[i];
        dinv[i] = (d > 0.0f) ? rsqrtf(d) : 0.0f;
    }
}

// single-block exclusive scan over counts -> row_ptr (and cursor copy)
__global__ void scan_kernel(const int* __restrict__ counts,
                            int* row_ptr, int* cursor, int n) {
    __shared__ int buf[1024];
    __shared__ int carry;
    int tid = threadIdx.x;
    if (tid == 0) carry = 0;
    __syncthreads();
    for (int base = 0; base < n; base += 1024) {
        int i = base + tid;
        int v = (i < n) ? counts[i] : 0;
        buf[tid] = v;
        __syncthreads();
        for (int off = 1; off < 1024; off <<= 1) {
            int t = (tid >= off) ? buf[tid - off] : 0;
            __syncthreads();
            buf[tid] += t;
            __syncthreads();
        }
        int excl = buf[tid] - v + carry;  // reads carry before update below
        if (i < n) { row_ptr[i] = excl; cursor[i] = excl; }
        __syncthreads();
        if (tid == 1023) carry += buf[1023];
        __syncthreads();
    }
    if (tid == 0) row_ptr[n] = carry;
}

__global__ void fill_kernel(const int* __restrict__ src, const int* __restrict__ dst,
                            const float* __restrict__ w, const float* __restrict__ dinv,
                            int* cursor, int* src_s, float* norm_s, int E) {
    int e = blockIdx.x * blockDim.x + threadIdx.x;
    if (e < E) {
        int s = src[e], d = dst[e];
        int p = atomicAdd(&cursor[d], 1);
        src_s[p] = s;
        norm_s[p] = dinv[s] * w[e] * dinv[d];
    }
}

// xw[N,384] = node_feat[N,128] @ W_g[128,128] for g in {z,r,h}
__global__ __launch_bounds__(128) void gemm_xw_kernel(
        const float* __restrict__ A,
        const float* __restrict__ Wz, const float* __restrict__ Wr,
        const float* __restrict__ Wh, float* __restrict__ xw, int n) {
    __shared__ float As[32][HD];
    int g = blockIdx.y;
    const float* W = (g == 0) ? Wz : (g == 1) ? Wr : Wh;
    int row0 = blockIdx.x * 32;
    int t = threadIdx.x;  // 0..127 = output column
    for (int r = 0; r < 32; ++r) {
        int row = row0 + r;
        As[r][t] = (row < n) ? A[(size_t)row * HD + t] : 0.0f;
    }
    __syncthreads();
    float acc[32];
#pragma unroll
    for (int r = 0; r < 32; ++r) acc[r] = 0.0f;
    for (int k = 0; k < HD; ++k) {
        float wv = W[k * HD + t];
#pragma unroll
        for (int r = 0; r < 32; ++r) acc[r] += As[r][k] * wv;
    }
    for (int r = 0; r < 32; ++r) {
        int row = row0 + r;
        if (row < n) xw[(size_t)row * G3 + g * HD + t] = acc[r];
    }
}

// Per 8 nodes: CSR gather-aggregate 3 gates, then full GRU cell fused.
__global__ __launch_bounds__(384) void fused_agg_gru_kernel(
        const float* __restrict__ xw, const float* __restrict__ h0,
        const float* __restrict__ dinv,
        const int* __restrict__ row_ptr, const int* __restrict__ src_s,
        const float* __restrict__ norm_s,
        const float* __restrict__ bz, const float* __restrict__ br,
        const float* __restrict__ bh,
        const float* __restrict__ lzW, const float* __restrict__ lzb,
        const float* __restrict__ lrW, const float* __restrict__ lrb,
        const float* __restrict__ lhW, const float* __restrict__ lhb,
        float* __restrict__ hout, int n) {
    __shared__ float agg[8][G3];
    __shared__ float h0s[8][HD];
    __shared__ float zg[8][HD];
    __shared__ float rg[8][HD];
    __shared__ float hp[8][HD];
    __shared__ float hq[8][HD];
    int t = threadIdx.x;            // 0..383
    int i0 = blockIdx.x * 8;
    int nvalid = min(8, n - i0);

    // Phase A: aggregate (self-loop + in-edges) per node, add gcn bias
    for (int nn = 0; nn < nvalid; ++nn) {
        int i = i0 + nn;
        float di = dinv[i];
        float a = di * di * xw[(size_t)i * G3 + t];
        int e0 = row_ptr[i], e1 = row_ptr[i + 1];
        for (int e = e0; e < e1; ++e) {
            a += norm_s[e] * xw[(size_t)src_s[e] * G3 + t];
        }
        float b = (t < 128) ? bz[t] : (t < 256) ? br[t - 128] : bh[t - 256];
        agg[nn][t] = a + b;
        if (t < HD) h0s[nn][t] = h0[(size_t)i * HD + t];
    }
    __syncthreads();

    // Phase B1: z_pre, r_pre (full 2H matvec), h partial (gcn_h part only)
    {
        int g = t >> 7, j = t & 127;
        const float* lW = (g == 0) ? lzW : (g == 1) ? lrW : lhW;
        const float* lb = (g == 0) ? lzb : (g == 1) ? lrb : lhb;
        float acc[8];
#pragma unroll
        for (int nn = 0; nn < 8; ++nn) acc[nn] = lb[j];
        if (g < 2) {
            for (int k = 0; k < HD; ++k) {
                float w1 = lW[k * HD + j];
                float w2 = lW[(HD + k) * HD + j];
#pragma unroll
                for (int nn = 0; nn < 8; ++nn)
                    acc[nn] += agg[nn][(g << 7) + k] * w1 + h0s[nn][k] * w2;
            }
            if (g == 0) {
#pragma unroll
                for (int nn = 0; nn < 8; ++nn)
                    zg[nn][j] = 1.0f / (1.0f + expf(-acc[nn]));
            } else {
#pragma unroll
                for (int nn = 0; nn < 8; ++nn)
                    rg[nn][j] = 1.0f / (1.0f + expf(-acc[nn]));
            }
        } else {
            for (int k = 0; k < HD; ++k) {
                float w1 = lW[k * HD + j];
#pragma unroll
                for (int nn = 0; nn < 8; ++nn)
                    acc[nn] += agg[nn][256 + k] * w1;
            }
#pragma unroll
            for (int nn = 0; nn < 8; ++nn) hp[nn][j] = acc[nn];
        }
    }
    __syncthreads();
    // hq = h0 * r_g
    for (int idx = t; idx < 8 * HD; idx += 384) {
        int nn = idx >> 7, k = idx & 127;
        hq[nn][k] = h0s[nn][k] * rg[nn][k];
    }
    __syncthreads();

    // Phase B2: finish h gate, GRU combine, write h_new
    if (t < HD) {
        int j = t;
        float acc[8];
#pragma unroll
        for (int nn = 0; nn < 8; ++nn) acc[nn] = hp[nn][j];
        for (int k = 0; k < HD; ++k) {
            float w2 = lhW[(HD + k) * HD + j];
#pragma unroll
            for (int nn = 0; nn < 8; ++nn) acc[nn] += hq[nn][k] * w2;
        }
        for (int nn = 0; nn < nvalid; ++nn) {
            float z = zg[nn][j];
            float ht = tanhf(acc[nn]);
            hout[(size_t)(i0 + nn) * HD + j] = z * h0s[nn][j] + (1.0f - z) * ht;
        }
    }
}

__global__ __launch_bounds__(128) void pool_kernel(
        const float* __restrict__ hout, const int* __restrict__ nids,
        float* pooled, int U) {
    int t = threadIdx.x;  // column
    float pa = 0.0f;
    for (int u = blockIdx.x; u < U; u += gridDim.x) {
        int nid = nids[u];
        pa += fmaxf(hout[(size_t)nid * HD + t], 0.0f);
    }
    atomicAdd(&pooled[t], pa);
}

__global__ __launch_bounds__(128) void decoder_kernel(
        const float* __restrict__ pooled, float invU,
        const float* __restrict__ linW, const float* __restrict__ linb,
        const float* __restrict__ dnW, const float* __restrict__ dnb,
        const float* __restrict__ outW, const float* __restrict__ outb,
        float* pred, int C) {
    __shared__ float sh[HD];
    int t = threadIdx.x;
    sh[t] = pooled[t] * invU;
    __syncthreads();
    float v = linb[t];
    for (int k = 0; k < HD; ++k) v += sh[k] * linW[k * HD + t];
    __syncthreads();
    sh[t] = v;  // z_graph (no relu here; relu was applied pre-pooling)
    __syncthreads();
    float d = dnb[t];
    for (int k = 0; k < HD; ++k) d += sh[k] * dnW[k * HD + t];
    d = fmaxf(d, 0.0f);
    __syncthreads();
    sh[t] = d;
    __syncthreads();
    if (t < C) {
        float p = outb[t];
        for (int k = 0; k < HD; ++k) p += sh[k] * outW[k * C + t];
        pred[t] = 1.0f / (1.0f + expf(-p));
    }
}

extern "C" void kernel_launch(void* const* d_in, const int* in_sizes, int n_in,
                              void* d_out, int out_size, void* d_ws, size_t ws_size,
                              hipStream_t stream) {
    const float* node_feat = (const float*)d_in[0];
    const float* edge_w    = (const float*)d_in[1];
    const float* h0        = (const float*)d_in[2];
    const float* Wz  = (const float*)d_in[3];  const float* bz  = (const float*)d_in[4];
    const float* Wr  = (const float*)d_in[5];  const float* br  = (const float*)d_in[6];
    const float* Wh  = (const float*)d_in[7];  const float* bh  = (const float*)d_in[8];
    const float* lzW = (const float*)d_in[9];  const float* lzb = (const float*)d_in[10];
    const float* lrW = (const float*)d_in[11]; const float* lrb = (const float*)d_in[12];
    const float* lhW = (const float*)d_in[13]; const float* lhb = (const float*)d_in[14];
    const float* linW= (const float*)d_in[15]; const float* linb= (const float*)d_in[16];
    const float* dnW = (const float*)d_in[17]; const float* dnb = (const float*)d_in[18];
    const float* outW= (const float*)d_in[19]; const float* outb= (const float*)d_in[20];
    const int* src  = (const int*)d_in[21];
    const int* dst  = (const int*)d_in[22];
    const int* nids = (const int*)d_in[23];

    const int N = in_sizes[2] / HD;   // h0 is [N,H]
    const int E = in_sizes[1];
    const int U = in_sizes[23];
    const int C = in_sizes[20];

    float* out  = (float*)d_out;
    float* pred = out;          // [C]
    float* hout = out + C;      // [N,H]

    // workspace layout
    float* xw     = (float*)d_ws;                 // N*384
    float* deg    = xw + (size_t)N * G3;          // N
    float* dinv   = deg + N;                      // N
    float* norm_s = dinv + N;                     // E
    float* pooled = norm_s + E;                   // 128
    int*   counts = (int*)(pooled + HD);          // N
    int*   row_ptr= counts + N;                   // N+1
    int*   cursor = row_ptr + (N + 1);            // N
    int*   src_s  = cursor + N;                   // E

    hipMemsetAsync(counts, 0, (size_t)N * sizeof(int), stream);
    hipMemsetAsync(pooled, 0, HD * sizeof(float), stream);

    init_deg_kernel<<<(N + 255) / 256, 256, 0, stream>>>(deg, N);
    edge_accum_kernel<<<(E + 255) / 256, 256, 0, stream>>>(dst, edge_w, deg, counts, E);
    dinv_kernel<<<(N + 255) / 256, 256, 0, stream>>>(deg, dinv, N);
    scan_kernel<<<1, 1024, 0, stream>>>(counts, row_ptr, cursor, N);
    fill_kernel<<<(E + 255) / 256, 256, 0, stream>>>(src, dst, edge_w, dinv, cursor,
                                                     src_s, norm_s, E);
    dim3 gg((N + 31) / 32, 3);
    gemm_xw_kernel<<<gg, 128, 0, stream>>>(node_feat, Wz, Wr, Wh, xw, N);
    fused_agg_gru_kernel<<<(N + 7) / 8, 384, 0, stream>>>(
        xw, h0, dinv, row_ptr, src_s, norm_s, bz, br, bh,
        lzW, lzb, lrW, lrb, lhW, lhb, hout, N);
    pool_kernel<<<200, 128, 0, stream>>>(hout, nids, pooled, U);
    decoder_kernel<<<1, 128, 0, stream>>>(pooled, 1.0f / (float)U,
                                          linW, linb, dnW, dnb, outW, outb, pred, C);
}

// Round 2
// 798.364 us; speedup vs baseline: 1.3275x; 1.3275x over previous
//
#include <hip/hip_runtime.h>
#include <math.h>

// TGCN restructured: aggregate in FEATURE space (gather 128 wide, table 25.6MB),
// then fused per-tile GEMM (Wz|Wr|Wh) + GRU cell. CSR-by-dst, no float atomics.

#define HD 128
#define NB 16   // nodes per gemm_gru block

__global__ void init_deg_kernel(float* deg, int n) {
    int i = blockIdx.x * blockDim.x + threadIdx.x;
    if (i < n) deg[i] = 1.0f;  // self-loop weight
}

__global__ void edge_accum_kernel(const int* __restrict__ dst,
                                  const float* __restrict__ w,
                                  float* deg, int* counts, int E) {
    int e = blockIdx.x * blockDim.x + threadIdx.x;
    if (e < E) {
        int d = dst[e];
        atomicAdd(&deg[d], w[e]);
        atomicAdd(&counts[d], 1);
    }
}

__global__ void dinv_kernel(const float* __restrict__ deg, float* dinv, int n) {
    int i = blockIdx.x * blockDim.x + threadIdx.x;
    if (i < n) {
        float d = deg[i];
        dinv[i] = (d > 0.0f) ? rsqrtf(d) : 0.0f;
    }
}

// single-block scan (shuffle-based, few barriers) counts -> row_ptr, cursor
__global__ __launch_bounds__(1024) void scan_kernel(const int* __restrict__ counts,
                                                    int* row_ptr, int* cursor, int n) {
    __shared__ int wsum[16];
    __shared__ int carry_s;
    int tid = threadIdx.x;
    int lane = tid & 63, wid = tid >> 6;
    if (tid == 0) carry_s = 0;
    __syncthreads();
    for (int base = 0; base < n; base += 1024) {
        int i = base + tid;
        int v = (i < n) ? counts[i] : 0;
        int x = v;  // inclusive wave scan
        for (int off = 1; off < 64; off <<= 1) {
            int y = __shfl_up(x, off, 64);
            if (lane >= off) x += y;
        }
        if (lane == 63) wsum[wid] = x;
        __syncthreads();
        if (wid == 0) {
            int s = (lane < 16) ? wsum[lane] : 0;
            for (int off = 1; off < 16; off <<= 1) {
                int y = __shfl_up(s, off, 64);
                if (lane >= off) s += y;
            }
            if (lane < 16) wsum[lane] = s;
        }
        __syncthreads();
        int carry = carry_s;
        int woff = (wid == 0) ? 0 : wsum[wid - 1];
        int excl = carry + woff + x - v;
        if (i < n) { row_ptr[i] = excl; cursor[i] = excl; }
        __syncthreads();
        if (tid == 1023) carry_s += wsum[15];
        __syncthreads();
    }
    if (tid == 0) row_ptr[n] = carry_s;
}

__global__ void fill_kernel(const int* __restrict__ src, const int* __restrict__ dst,
                            const float* __restrict__ w, const float* __restrict__ dinv,
                            int* cursor, int* src_s, float* norm_s, int E) {
    int e = blockIdx.x * blockDim.x + threadIdx.x;
    if (e < E) {
        int s = src[e], d = dst[e];
        int p = atomicAdd(&cursor[d], 1);
        src_s[p] = s;
        norm_s[p] = dinv[s] * w[e] * dinv[d];
    }
}

// agg[i,:] = dinv[i]^2 * nf[i,:] + sum_e norm[e] * nf[src[e],:]   (128 wide)
__global__ __launch_bounds__(256) void agg_feat_kernel(
        const float* __restrict__ nf, const float* __restrict__ dinv,
        const int* __restrict__ row_ptr, const int* __restrict__ src_s,
        const float* __restrict__ norm_s, float* __restrict__ agg, int n) {
    int t = threadIdx.x & 127;
    int grp = threadIdx.x >> 7;
    int i = blockIdx.x * 2 + grp;
    if (i >= n) return;
    float di = dinv[i];
    float a = di * di * nf[(size_t)i * HD + t];
    int e0 = row_ptr[i], e1 = row_ptr[i + 1];
    for (int e = e0; e < e1; e += 8) {
        float v[8], w[8];
#pragma unroll
        for (int u = 0; u < 8; ++u) {
            int ee = e + u;
            bool ok = ee < e1;
            int s = ok ? src_s[ee] : src_s[e0];
            w[u] = ok ? norm_s[ee] : 0.0f;
            v[u] = nf[(size_t)s * HD + t];
        }
#pragma unroll
        for (int u = 0; u < 8; ++u) a += w[u] * v[u];
    }
    agg[(size_t)i * HD + t] = a;
}

// Per 16-node tile: c_g = agg@Wg + bg (g=z,r,h); z,r = sigmoid([c,h0]@lW+lb);
// h_t = tanh([c_h, h0*r]@lhW+lhb); h_new = z*h0+(1-z)*h_t
__global__ __launch_bounds__(384) void gemm_gru_kernel(
        const float* __restrict__ agg, const float* __restrict__ h0,
        const float* __restrict__ Wz, const float* __restrict__ Wr,
        const float* __restrict__ Wh,
        const float* __restrict__ bz, const float* __restrict__ br,
        const float* __restrict__ bh,
        const float* __restrict__ lzW, const float* __restrict__ lzb,
        const float* __restrict__ lrW, const float* __restrict__ lrb,
        const float* __restrict__ lhW, const float* __restrict__ lhb,
        float* __restrict__ hout, int n) {
    __shared__ float As[NB][HD];   // agg tile; reused as hq = h0*r
    __shared__ float Hs[NB][HD];   // h0 tile
    __shared__ float Cz[NB][HD];   // gcn_z -> z gate
    __shared__ float Cr[NB][HD];   // gcn_r -> r gate
    __shared__ float Ch[NB][HD];   // gcn_h -> h partial
    int t = threadIdx.x;
    int i0 = blockIdx.x * NB;
    int nvalid = min(NB, n - i0);

    for (int idx = t; idx < NB * HD; idx += 384) {
        int r = idx >> 7, c = idx & 127;
        int i = i0 + r;
        bool ok = r < nvalid;
        As[r][c] = ok ? agg[(size_t)i * HD + c] : 0.0f;
        Hs[r][c] = ok ? h0[(size_t)i * HD + c] : 0.0f;
    }
    __syncthreads();

    int g = t >> 7, j = t & 127;
    const float* W  = (g == 0) ? Wz : (g == 1) ? Wr : Wh;
    const float* bb = (g == 0) ? bz : (g == 1) ? br : bh;
    float* Cg = (g == 0) ? &Cz[0][0] : (g == 1) ? &Cr[0][0] : &Ch[0][0];

    float acc[NB];
    {
        float b = bb[j];
#pragma unroll
        for (int r = 0; r < NB; ++r) acc[r] = b;
    }
    for (int k = 0; k < HD; k += 4) {
        float w0 = W[(k + 0) * HD + j], w1 = W[(k + 1) * HD + j];
        float w2 = W[(k + 2) * HD + j], w3 = W[(k + 3) * HD + j];
#pragma unroll
        for (int r = 0; r < NB; ++r) {
            float4 a4 = *(const float4*)&As[r][k];
            acc[r] += a4.x * w0 + a4.y * w1 + a4.z * w2 + a4.w * w3;
        }
    }
#pragma unroll
    for (int r = 0; r < NB; ++r) Cg[r * HD + j] = acc[r];
    __syncthreads();

    // gates
    const float* lW = (g == 0) ? lzW : (g == 1) ? lrW : lhW;
    const float* lb = (g == 0) ? lzb : (g == 1) ? lrb : lhb;
    {
        float b = lb[j];
#pragma unroll
        for (int r = 0; r < NB; ++r) acc[r] = b;
    }
    if (g < 2) {
        for (int k = 0; k < HD; k += 4) {
            float a0 = lW[(k + 0) * HD + j], a1 = lW[(k + 1) * HD + j];
            float a2 = lW[(k + 2) * HD + j], a3 = lW[(k + 3) * HD + j];
            float b0 = lW[(HD + k + 0) * HD + j], b1 = lW[(HD + k + 1) * HD + j];
            float b2 = lW[(HD + k + 2) * HD + j], b3 = lW[(HD + k + 3) * HD + j];
#pragma unroll
            for (int r = 0; r < NB; ++r) {
                float4 c4 = *(const float4*)&Cg[r * HD + k];
                float4 h4 = *(const float4*)&Hs[r][k];
                acc[r] += c4.x * a0 + c4.y * a1 + c4.z * a2 + c4.w * a3
                        + h4.x * b0 + h4.y * b1 + h4.z * b2 + h4.w * b3;
            }
        }
#pragma unroll
        for (int r = 0; r < NB; ++r) acc[r] = 1.0f / (1.0f + expf(-acc[r]));
    } else {
        for (int k = 0; k < HD; k += 4) {
            float a0 = lW[(k + 0) * HD + j], a1 = lW[(k + 1) * HD + j];
            float a2 = lW[(k + 2) * HD + j], a3 = lW[(k + 3) * HD + j];
#pragma unroll
            for (int r = 0; r < NB; ++r) {
                float4 c4 = *(const float4*)&Cg[r * HD + k];
                acc[r] += c4.x * a0 + c4.y * a1 + c4.z * a2 + c4.w * a3;
            }
        }
    }
    __syncthreads();   // all reads of Cz/Cr/Ch done
#pragma unroll
    for (int r = 0; r < NB; ++r) Cg[r * HD + j] = acc[r];  // zg, rg, hpart
    __syncthreads();

    // hq = h0 * r  into As
    for (int idx = t; idx < NB * HD; idx += 384) {
        int r = idx >> 7, c = idx & 127;
        As[r][c] = Hs[r][c] * Cr[r][c];
    }
    __syncthreads();

    // finish h gate + GRU combine; nodes strided across the 3 gate-groups
    float acc2[6];
#pragma unroll
    for (int q = 0; q < 6; ++q) acc2[q] = 0.0f;
    for (int k = 0; k < HD; k += 4) {
        float b0 = lhW[(HD + k + 0) * HD + j], b1 = lhW[(HD + k + 1) * HD + j];
        float b2 = lhW[(HD + k + 2) * HD + j], b3 = lhW[(HD + k + 3) * HD + j];
#pragma unroll
        for (int q = 0; q < 6; ++q) {
            int r = g + 3 * q;
            if (r < NB) {
                float4 a4 = *(const float4*)&As[r][k];
                acc2[q] += a4.x * b0 + a4.y * b1 + a4.z * b2 + a4.w * b3;
            }
        }
    }
#pragma unroll
    for (int q = 0; q < 6; ++q) {
        int r = g + 3 * q;
        if (r < nvalid) {
            float ht = tanhf(Ch[r][j] + acc2[q]);
            float z = Cz[r][j];
            hout[(size_t)(i0 + r) * HD + j] = z * Hs[r][j] + (1.0f - z) * ht;
        }
    }
}

__global__ __launch_bounds__(128) void pool_kernel(
        const float* __restrict__ hout, const int* __restrict__ nids,
        float* pooled, int U) {
    int t = threadIdx.x;
    float pa = 0.0f;
    for (int u = blockIdx.x; u < U; u += gridDim.x) {
        int nid = nids[u];
        pa += fmaxf(hout[(size_t)nid * HD + t], 0.0f);
    }
    atomicAdd(&pooled[t], pa);
}

__global__ __launch_bounds__(128) void decoder_kernel(
        const float* __restrict__ pooled, float invU,
        const float* __restrict__ linW, const float* __restrict__ linb,
        const float* __restrict__ dnW, const float* __restrict__ dnb,
        const float* __restrict__ outW, const float* __restrict__ outb,
        float* pred, int C) {
    __shared__ float sh[HD];
    int t = threadIdx.x;
    sh[t] = pooled[t] * invU;
    __syncthreads();
    float v = linb[t];
    for (int k = 0; k < HD; ++k) v += sh[k] * linW[k * HD + t];
    __syncthreads();
    sh[t] = v;
    __syncthreads();
    float d = dnb[t];
    for (int k = 0; k < HD; ++k) d += sh[k] * dnW[k * HD + t];
    d = fmaxf(d, 0.0f);
    __syncthreads();
    sh[t] = d;
    __syncthreads();
    if (t < C) {
        float p = outb[t];
        for (int k = 0; k < HD; ++k) p += sh[k] * outW[k * C + t];
        pred[t] = 1.0f / (1.0f + expf(-p));
    }
}

extern "C" void kernel_launch(void* const* d_in, const int* in_sizes, int n_in,
                              void* d_out, int out_size, void* d_ws, size_t ws_size,
                              hipStream_t stream) {
    const float* node_feat = (const float*)d_in[0];
    const float* edge_w    = (const float*)d_in[1];
    const float* h0        = (const float*)d_in[2];
    const float* Wz  = (const float*)d_in[3];  const float* bz  = (const float*)d_in[4];
    const float* Wr  = (const float*)d_in[5];  const float* br  = (const float*)d_in[6];
    const float* Wh  = (const float*)d_in[7];  const float* bh  = (const float*)d_in[8];
    const float* lzW = (const float*)d_in[9];  const float* lzb = (const float*)d_in[10];
    const float* lrW = (const float*)d_in[11]; const float* lrb = (const float*)d_in[12];
    const float* lhW = (const float*)d_in[13]; const float* lhb = (const float*)d_in[14];
    const float* linW= (const float*)d_in[15]; const float* linb= (const float*)d_in[16];
    const float* dnW = (const float*)d_in[17]; const float* dnb = (const float*)d_in[18];
    const float* outW= (const float*)d_in[19]; const float* outb= (const float*)d_in[20];
    const int* src  = (const int*)d_in[21];
    const int* dst  = (const int*)d_in[22];
    const int* nids = (const int*)d_in[23];

    const int N = in_sizes[2] / HD;
    const int E = in_sizes[1];
    const int U = in_sizes[23];
    const int C = in_sizes[20];

    float* out  = (float*)d_out;
    float* pred = out;          // [C]
    float* hout = out + C;      // [N,H]

    // workspace layout
    float* agg    = (float*)d_ws;                 // N*128
    float* deg    = agg + (size_t)N * HD;         // N
    float* dinv   = deg + N;                      // N
    float* norm_s = dinv + N;                     // E
    float* pooled = norm_s + E;                   // 128
    int*   counts = (int*)(pooled + HD);          // N
    int*   row_ptr= counts + N;                   // N+1
    int*   cursor = row_ptr + (N + 1);            // N
    int*   src_s  = cursor + N;                   // E

    hipMemsetAsync(counts, 0, (size_t)N * sizeof(int), stream);
    hipMemsetAsync(pooled, 0, HD * sizeof(float), stream);

    init_deg_kernel<<<(N + 255) / 256, 256, 0, stream>>>(deg, N);
    edge_accum_kernel<<<(E + 255) / 256, 256, 0, stream>>>(dst, edge_w, deg, counts, E);
    dinv_kernel<<<(N + 255) / 256, 256, 0, stream>>>(deg, dinv, N);
    scan_kernel<<<1, 1024, 0, stream>>>(counts, row_ptr, cursor, N);
    fill_kernel<<<(E + 255) / 256, 256, 0, stream>>>(src, dst, edge_w, dinv, cursor,
                                                     src_s, norm_s, E);
    agg_feat_kernel<<<(N + 1) / 2, 256, 0, stream>>>(node_feat, dinv, row_ptr,
                                                     src_s, norm_s, agg, N);
    gemm_gru_kernel<<<(N + NB - 1) / NB, 384, 0, stream>>>(
        agg, h0, Wz, Wr, Wh, bz, br, bh,
        lzW, lzb, lrW, lrb, lhW, lhb, hout, N);
    pool_kernel<<<512, 128, 0, stream>>>(hout, nids, pooled, U);
    decoder_kernel<<<1, 128, 0, stream>>>(pooled, 1.0f / (float)U,
                                          linW, linb, dnW, dnb, outW, outb, pred, C);
}

// Round 3
// 457.671 us; speedup vs baseline: 2.3157x; 1.7444x over previous
//
#include <hip/hip_runtime.h>
#include <math.h>

// TGCN: feature-space GCN aggregation (fp32 gather) -> fused bf16-MFMA GRU.
// CSR-by-dst, no float atomic scatter. Weights pre-transposed to bf16 [col][k].

#define HD 128

typedef __attribute__((ext_vector_type(8))) short short8;
typedef __attribute__((ext_vector_type(4))) float f32x4;

__device__ __forceinline__ ushort f2bf(float f) {
    union { float f; unsigned u; } v; v.f = f;
    unsigned r = (v.u + 0x7FFFu + ((v.u >> 16) & 1u)) >> 16;
    return (ushort)r;
}
__device__ __forceinline__ float bf2f(ushort h) {
    union { unsigned u; float f; } v; v.u = ((unsigned)h) << 16;
    return v.f;
}

__global__ void init_deg_kernel(float* deg, int n) {
    int i = blockIdx.x * blockDim.x + threadIdx.x;
    if (i < n) deg[i] = 1.0f;  // self-loop weight
}

__global__ void edge_accum_kernel(const int* __restrict__ dst,
                                  const float* __restrict__ w,
                                  float* deg, int* counts, int E) {
    int e = blockIdx.x * blockDim.x + threadIdx.x;
    if (e < E) {
        int d = dst[e];
        atomicAdd(&deg[d], w[e]);
        atomicAdd(&counts[d], 1);
    }
}

__global__ void dinv_kernel(const float* __restrict__ deg, float* dinv, int n) {
    int i = blockIdx.x * blockDim.x + threadIdx.x;
    if (i < n) {
        float d = deg[i];
        dinv[i] = (d > 0.0f) ? rsqrtf(d) : 0.0f;
    }
}

// single-block scan (shuffle-based) counts -> row_ptr, cursor
__global__ __launch_bounds__(1024) void scan_kernel(const int* __restrict__ counts,
                                                    int* row_ptr, int* cursor, int n) {
    __shared__ int wsum[16];
    __shared__ int carry_s;
    int tid = threadIdx.x;
    int lane = tid & 63, wid = tid >> 6;
    if (tid == 0) carry_s = 0;
    __syncthreads();
    for (int base = 0; base < n; base += 1024) {
        int i = base + tid;
        int v = (i < n) ? counts[i] : 0;
        int x = v;
        for (int off = 1; off < 64; off <<= 1) {
            int y = __shfl_up(x, off, 64);
            if (lane >= off) x += y;
        }
        if (lane == 63) wsum[wid] = x;
        __syncthreads();
        if (wid == 0) {
            int s = (lane < 16) ? wsum[lane] : 0;
            for (int off = 1; off < 16; off <<= 1) {
                int y = __shfl_up(s, off, 64);
                if (lane >= off) s += y;
            }
            if (lane < 16) wsum[lane] = s;
        }
        __syncthreads();
        int carry = carry_s;
        int woff = (wid == 0) ? 0 : wsum[wid - 1];
        int excl = carry + woff + x - v;
        if (i < n) { row_ptr[i] = excl; cursor[i] = excl; }
        __syncthreads();
        if (tid == 1023) carry_s += wsum[15];
        __syncthreads();
    }
    if (tid == 0) row_ptr[n] = carry_s;
}

__global__ void fill_kernel(const int* __restrict__ src, const int* __restrict__ dst,
                            const float* __restrict__ w, const float* __restrict__ dinv,
                            int* cursor, int* src_s, float* norm_s, int E) {
    int e = blockIdx.x * blockDim.x + threadIdx.x;
    if (e < E) {
        int s = src[e], d = dst[e];
        int p = atomicAdd(&cursor[d], 1);
        src_s[p] = s;
        norm_s[p] = dinv[s] * w[e] * dinv[d];
    }
}

// dst[j*K + k] = bf16(src[k*J + j])   (transpose + cvt)
__global__ void transpose_bf16_kernel(const float* __restrict__ src,
                                      ushort* __restrict__ dst, int K, int J) {
    int idx = blockIdx.x * 256 + threadIdx.x;
    if (idx < K * J) {
        int j = idx / K, k = idx - j * K;
        dst[idx] = f2bf(src[k * J + j]);
    }
}

// aggb[i,:] = bf16( dinv[i]^2 * nf[i,:] + sum_e norm[e] * nf[src[e],:] )
__global__ __launch_bounds__(256) void agg_feat_kernel(
        const float* __restrict__ nf, const float* __restrict__ dinv,
        const int* __restrict__ row_ptr, const int* __restrict__ src_s,
        const float* __restrict__ norm_s, ushort* __restrict__ aggb, int n) {
    int t = threadIdx.x & 127;
    int grp = threadIdx.x >> 7;
    int i = blockIdx.x * 2 + grp;
    if (i >= n) return;
    float di = dinv[i];
    float a = di * di * nf[(size_t)i * HD + t];
    int e0 = row_ptr[i], e1 = row_ptr[i + 1];
    for (int e = e0; e < e1; e += 8) {
        float v[8], w[8];
#pragma unroll
        for (int u = 0; u < 8; ++u) {
            int ee = e + u;
            bool ok = ee < e1;
            int s = ok ? src_s[ee] : src_s[e0];
            w[u] = ok ? norm_s[ee] : 0.0f;
            v[u] = nf[(size_t)s * HD + t];
        }
#pragma unroll
        for (int u = 0; u < 8; ++u) a += w[u] * v[u];
    }
    aggb[(size_t)i * HD + t] = f2bf(a);
}

// Fused GRU via bf16 MFMA. 32-node tile, 6 waves:
//   waves 0,1 -> z cols 0..127 ; waves 2,3 -> r ; waves 4,5 -> h
__global__ __launch_bounds__(384) void gru_mfma_kernel(
        const ushort* __restrict__ aggb, const float* __restrict__ h0,
        const ushort* __restrict__ WcatT,
        const ushort* __restrict__ lzT, const ushort* __restrict__ lrT,
        const ushort* __restrict__ lhT,
        const float* __restrict__ bz, const float* __restrict__ br,
        const float* __restrict__ bh,
        const float* __restrict__ lzb, const float* __restrict__ lrb,
        const float* __restrict__ lhb,
        float* __restrict__ hout, int n) {
    __shared__ ushort Aag[32][136];   // agg tile bf16 (pad 8 -> stride 272B)
    __shared__ ushort Ah0[32][136];   // h0 tile bf16
    __shared__ ushort C1s[32][392];   // C1 = agg@Wcat + b  (384 cols, pad 8)
    __shared__ ushort hqs[32][136];   // h0*r
    __shared__ ushort zsb[32][128];   // z gate
    int t = threadIdx.x;
    int i0 = blockIdx.x * 32;

    // stage agg + h0 tiles (rows >= n zero-filled)
    for (int idx = t; idx < 512; idx += 384) {
        int row = idx >> 4, c8 = idx & 15;
        int node = i0 + row;
        if (node < n) {
            *(short8*)&Aag[row][c8 * 8] =
                *(const short8*)(aggb + (size_t)node * HD + c8 * 8);
            const float* hp = h0 + (size_t)node * HD + c8 * 8;
            float4 ha = *(const float4*)hp;
            float4 hb = *(const float4*)(hp + 4);
            short8 hv;
            hv[0] = (short)f2bf(ha.x); hv[1] = (short)f2bf(ha.y);
            hv[2] = (short)f2bf(ha.z); hv[3] = (short)f2bf(ha.w);
            hv[4] = (short)f2bf(hb.x); hv[5] = (short)f2bf(hb.y);
            hv[6] = (short)f2bf(hb.z); hv[7] = (short)f2bf(hb.w);
            *(short8*)&Ah0[row][c8 * 8] = hv;
        } else {
            short8 zz = {0, 0, 0, 0, 0, 0, 0, 0};
            *(short8*)&Aag[row][c8 * 8] = zz;
            *(short8*)&Ah0[row][c8 * 8] = zz;
        }
    }
    __syncthreads();

    int wave = t >> 6, lane = t & 63;
    int g = wave >> 1;                 // gate: 0=z 1=r 2=h
    int colbase = wave * 64;           // global col in [0,384)
    int lc0 = (wave & 1) * 64;         // col within gate
    int rlo = lane & 15;
    int koff = (lane >> 4) * 8;
    int rbase = (lane >> 4) * 4;       // C/D row group

    f32x4 acc[2][4];
    const f32x4 zero4 = {0.f, 0.f, 0.f, 0.f};
#pragma unroll
    for (int rf = 0; rf < 2; ++rf)
#pragma unroll
        for (int cf = 0; cf < 4; ++cf) acc[rf][cf] = zero4;

    // ---- Phase 1: C1 = agg @ Wcat  (K=128) ----
#pragma unroll
    for (int ks = 0; ks < 4; ++ks) {
        short8 af0 = *(const short8*)&Aag[rlo][ks * 32 + koff];
        short8 af1 = *(const short8*)&Aag[16 + rlo][ks * 32 + koff];
        short8 bf[4];
#pragma unroll
        for (int cf = 0; cf < 4; ++cf) {
            int col = colbase + cf * 16 + rlo;
            bf[cf] = *(const short8*)(WcatT + (size_t)col * 128 + ks * 32 + koff);
        }
#pragma unroll
        for (int cf = 0; cf < 4; ++cf) {
            acc[0][cf] = __builtin_amdgcn_mfma_f32_16x16x32_bf16(af0, bf[cf], acc[0][cf], 0, 0, 0);
            acc[1][cf] = __builtin_amdgcn_mfma_f32_16x16x32_bf16(af1, bf[cf], acc[1][cf], 0, 0, 0);
        }
    }
    {
        const float* gb = (g == 0) ? bz : (g == 1) ? br : bh;
#pragma unroll
        for (int cf = 0; cf < 4; ++cf) {
            int bcol = lc0 + cf * 16 + rlo;
            int col = colbase + cf * 16 + rlo;
            float bv = gb[bcol];
#pragma unroll
            for (int rf = 0; rf < 2; ++rf)
#pragma unroll
                for (int i = 0; i < 4; ++i) {
                    int row = rf * 16 + rbase + i;
                    C1s[row][col] = f2bf(acc[rf][cf][i] + bv);
                }
        }
    }
    __syncthreads();

    // ---- Phase 2: gates ----
#pragma unroll
    for (int rf = 0; rf < 2; ++rf)
#pragma unroll
        for (int cf = 0; cf < 4; ++cf) acc[rf][cf] = zero4;

    const ushort* lT = (g == 0) ? lzT : (g == 1) ? lrT : lhT;
    if (g < 2) {
        // [C1g | h0] @ lT   (K=256)
#pragma unroll
        for (int ks = 0; ks < 4; ++ks) {
            short8 af0 = *(const short8*)&C1s[rlo][g * 128 + ks * 32 + koff];
            short8 af1 = *(const short8*)&C1s[16 + rlo][g * 128 + ks * 32 + koff];
            short8 bf[4];
#pragma unroll
            for (int cf = 0; cf < 4; ++cf) {
                int jc = lc0 + cf * 16 + rlo;
                bf[cf] = *(const short8*)(lT + (size_t)jc * 256 + ks * 32 + koff);
            }
#pragma unroll
            for (int cf = 0; cf < 4; ++cf) {
                acc[0][cf] = __builtin_amdgcn_mfma_f32_16x16x32_bf16(af0, bf[cf], acc[0][cf], 0, 0, 0);
                acc[1][cf] = __builtin_amdgcn_mfma_f32_16x16x32_bf16(af1, bf[cf], acc[1][cf], 0, 0, 0);
            }
        }
#pragma unroll
        for (int ks = 0; ks < 4; ++ks) {
            short8 af0 = *(const short8*)&Ah0[rlo][ks * 32 + koff];
            short8 af1 = *(const short8*)&Ah0[16 + rlo][ks * 32 + koff];
            short8 bf[4];
#pragma unroll
            for (int cf = 0; cf < 4; ++cf) {
                int jc = lc0 + cf * 16 + rlo;
                bf[cf] = *(const short8*)(lT + (size_t)jc * 256 + 128 + ks * 32 + koff);
            }
#pragma unroll
            for (int cf = 0; cf < 4; ++cf) {
                acc[0][cf] = __builtin_amdgcn_mfma_f32_16x16x32_bf16(af0, bf[cf], acc[0][cf], 0, 0, 0);
                acc[1][cf] = __builtin_amdgcn_mfma_f32_16x16x32_bf16(af1, bf[cf], acc[1][cf], 0, 0, 0);
            }
        }
        const float* lb = (g == 0) ? lzb : lrb;
#pragma unroll
        for (int cf = 0; cf < 4; ++cf) {
            int bcol = lc0 + cf * 16 + rlo;
            float bv = lb[bcol];
#pragma unroll
            for (int rf = 0; rf < 2; ++rf)
#pragma unroll
                for (int i = 0; i < 4; ++i) {
                    int row = rf * 16 + rbase + i;
                    float s = 1.0f / (1.0f + expf(-(acc[rf][cf][i] + bv)));
                    if (g == 0) {
                        zsb[row][bcol] = f2bf(s);
                    } else {
                        float hv = bf2f(Ah0[row][bcol]);
                        hqs[row][bcol] = f2bf(s * hv);
                    }
                }
        }
    } else {
        // hp = C1h @ lhT_top   (K=128), keep in regs
#pragma unroll
        for (int ks = 0; ks < 4; ++ks) {
            short8 af0 = *(const short8*)&C1s[rlo][256 + ks * 32 + koff];
            short8 af1 = *(const short8*)&C1s[16 + rlo][256 + ks * 32 + koff];
            short8 bf[4];
#pragma unroll
            for (int cf = 0; cf < 4; ++cf) {
                int jc = lc0 + cf * 16 + rlo;
                bf[cf] = *(const short8*)(lT + (size_t)jc * 256 + ks * 32 + koff);
            }
#pragma unroll
            for (int cf = 0; cf < 4; ++cf) {
                acc[0][cf] = __builtin_amdgcn_mfma_f32_16x16x32_bf16(af0, bf[cf], acc[0][cf], 0, 0, 0);
                acc[1][cf] = __builtin_amdgcn_mfma_f32_16x16x32_bf16(af1, bf[cf], acc[1][cf], 0, 0, 0);
            }
        }
    }
    __syncthreads();

    // ---- Phase 3 (h waves): hp += (h0*r) @ lhT_bot; combine; write ----
    if (g == 2) {
#pragma unroll
        for (int ks = 0; ks < 4; ++ks) {
            short8 af0 = *(const short8*)&hqs[rlo][ks * 32 + koff];
            short8 af1 = *(const short8*)&hqs[16 + rlo][ks * 32 + koff];
            short8 bf[4];
#pragma unroll
            for (int cf = 0; cf < 4; ++cf) {
                int jc = lc0 + cf * 16 + rlo;
                bf[cf] = *(const short8*)(lhT + (size_t)jc * 256 + 128 + ks * 32 + koff);
            }
#pragma unroll
            for (int cf = 0; cf < 4; ++cf) {
                acc[0][cf] = __builtin_amdgcn_mfma_f32_16x16x32_bf16(af0, bf[cf], acc[0][cf], 0, 0, 0);
                acc[1][cf] = __builtin_amdgcn_mfma_f32_16x16x32_bf16(af1, bf[cf], acc[1][cf], 0, 0, 0);
            }
        }
#pragma unroll
        for (int cf = 0; cf < 4; ++cf) {
            int bcol = lc0 + cf * 16 + rlo;
            float bv = lhb[bcol];
#pragma unroll
            for (int rf = 0; rf < 2; ++rf)
#pragma unroll
                for (int i = 0; i < 4; ++i) {
                    int row = rf * 16 + rbase + i;
                    int node = i0 + row;
                    if (node < n) {
                        float ht = tanhf(acc[rf][cf][i] + bv);
                        float z = bf2f(zsb[row][bcol]);
                        float h0v = bf2f(Ah0[row][bcol]);
                        hout[(size_t)node * HD + bcol] = z * h0v + (1.0f - z) * ht;
                    }
                }
        }
    }
}

__global__ __launch_bounds__(128) void pool_kernel(
        const float* __restrict__ hout, const int* __restrict__ nids,
        float* pooled, int U) {
    int t = threadIdx.x;
    float pa = 0.0f;
    for (int u = blockIdx.x; u < U; u += gridDim.x) {
        int nid = nids[u];
        pa += fmaxf(hout[(size_t)nid * HD + t], 0.0f);
    }
    atomicAdd(&pooled[t], pa);
}

__global__ __launch_bounds__(128) void decoder_kernel(
        const float* __restrict__ pooled, float invU,
        const float* __restrict__ linW, const float* __restrict__ linb,
        const float* __restrict__ dnW, const float* __restrict__ dnb,
        const float* __restrict__ outW, const float* __restrict__ outb,
        float* pred, int C) {
    __shared__ float sh[HD];
    int t = threadIdx.x;
    sh[t] = pooled[t] * invU;
    __syncthreads();
    float v = linb[t];
    for (int k = 0; k < HD; ++k) v += sh[k] * linW[k * HD + t];
    __syncthreads();
    sh[t] = v;
    __syncthreads();
    float d = dnb[t];
    for (int k = 0; k < HD; ++k) d += sh[k] * dnW[k * HD + t];
    d = fmaxf(d, 0.0f);
    __syncthreads();
    sh[t] = d;
    __syncthreads();
    if (t < C) {
        float p = outb[t];
        for (int k = 0; k < HD; ++k) p += sh[k] * outW[k * C + t];
        pred[t] = 1.0f / (1.0f + expf(-p));
    }
}

extern "C" void kernel_launch(void* const* d_in, const int* in_sizes, int n_in,
                              void* d_out, int out_size, void* d_ws, size_t ws_size,
                              hipStream_t stream) {
    const float* node_feat = (const float*)d_in[0];
    const float* edge_w    = (const float*)d_in[1];
    const float* h0        = (const float*)d_in[2];
    const float* Wz  = (const float*)d_in[3];  const float* bz  = (const float*)d_in[4];
    const float* Wr  = (const float*)d_in[5];  const float* br  = (const float*)d_in[6];
    const float* Wh  = (const float*)d_in[7];  const float* bh  = (const float*)d_in[8];
    const float* lzW = (const float*)d_in[9];  const float* lzb = (const float*)d_in[10];
    const float* lrW = (const float*)d_in[11]; const float* lrb = (const float*)d_in[12];
    const float* lhW = (const float*)d_in[13]; const float* lhb = (const float*)d_in[14];
    const float* linW= (const float*)d_in[15]; const float* linb= (const float*)d_in[16];
    const float* dnW = (const float*)d_in[17]; const float* dnb = (const float*)d_in[18];
    const float* outW= (const float*)d_in[19]; const float* outb= (const float*)d_in[20];
    const int* src  = (const int*)d_in[21];
    const int* dst  = (const int*)d_in[22];
    const int* nids = (const int*)d_in[23];

    const int N = in_sizes[2] / HD;
    const int E = in_sizes[1];
    const int U = in_sizes[23];
    const int C = in_sizes[20];

    float* out  = (float*)d_out;
    float* pred = out;          // [C]
    float* hout = out + C;      // [N,H]

    // workspace layout (16B-aligned chunks)
    char* p = (char*)d_ws;
    auto alloc = [&](size_t bytes) { char* r = p; p += (bytes + 15) & ~(size_t)15; return r; };
    float* deg    = (float*)alloc((size_t)N * 4);
    float* dinv   = (float*)alloc((size_t)N * 4);
    float* norm_s = (float*)alloc((size_t)E * 4);
    float* pooled = (float*)alloc(HD * 4);
    int*   counts = (int*)alloc((size_t)N * 4);
    int*   row_ptr= (int*)alloc((size_t)(N + 1) * 4);
    int*   cursor = (int*)alloc((size_t)N * 4);
    int*   src_s  = (int*)alloc((size_t)E * 4);
    ushort* aggb  = (ushort*)alloc((size_t)N * HD * 2);
    ushort* WcatT = (ushort*)alloc((size_t)384 * 128 * 2);
    ushort* lzT   = (ushort*)alloc((size_t)128 * 256 * 2);
    ushort* lrT   = (ushort*)alloc((size_t)128 * 256 * 2);
    ushort* lhT   = (ushort*)alloc((size_t)128 * 256 * 2);

    hipMemsetAsync(counts, 0, (size_t)N * sizeof(int), stream);
    hipMemsetAsync(pooled, 0, HD * sizeof(float), stream);

    init_deg_kernel<<<(N + 255) / 256, 256, 0, stream>>>(deg, N);
    edge_accum_kernel<<<(E + 255) / 256, 256, 0, stream>>>(dst, edge_w, deg, counts, E);
    dinv_kernel<<<(N + 255) / 256, 256, 0, stream>>>(deg, dinv, N);
    scan_kernel<<<1, 1024, 0, stream>>>(counts, row_ptr, cursor, N);
    fill_kernel<<<(E + 255) / 256, 256, 0, stream>>>(src, dst, edge_w, dinv, cursor,
                                                     src_s, norm_s, E);
    // weight transposes (bf16, [col][k])
    transpose_bf16_kernel<<<(128 * 128 + 255) / 256, 256, 0, stream>>>(Wz, WcatT, 128, 128);
    transpose_bf16_kernel<<<(128 * 128 + 255) / 256, 256, 0, stream>>>(Wr, WcatT + 128 * 128, 128, 128);
    transpose_bf16_kernel<<<(128 * 128 + 255) / 256, 256, 0, stream>>>(Wh, WcatT + 256 * 128, 128, 128);
    transpose_bf16_kernel<<<(256 * 128 + 255) / 256, 256, 0, stream>>>(lzW, lzT, 256, 128);
    transpose_bf16_kernel<<<(256 * 128 + 255) / 256, 256, 0, stream>>>(lrW, lrT, 256, 128);
    transpose_bf16_kernel<<<(256 * 128 + 255) / 256, 256, 0, stream>>>(lhW, lhT, 256, 128);

    agg_feat_kernel<<<(N + 1) / 2, 256, 0, stream>>>(node_feat, dinv, row_ptr,
                                                     src_s, norm_s, aggb, N);
    gru_mfma_kernel<<<(N + 31) / 32, 384, 0, stream>>>(
        aggb, h0, WcatT, lzT, lrT, lhT, bz, br, bh, lzb, lrb, lhb, hout, N);
    pool_kernel<<<512, 128, 0, stream>>>(hout, nids, pooled, U);
    decoder_kernel<<<1, 128, 0, stream>>>(pooled, 1.0f / (float)U,
                                          linW, linb, dnW, dnb, outW, outb, pred, C);
}